// Round 1
// 260.568 us; speedup vs baseline: 1.0021x; 1.0021x over previous
//
#include <hip/hip_runtime.h>

typedef unsigned int u32;
typedef _Float16 v2h __attribute__((ext_vector_type(2)));
typedef __fp16   v2fp __attribute__((ext_vector_type(2)));

#define E_TOT 160000
#define TPB   256
#define NBLK  1250        // (E/256)=625 tiles x 2 classes
#define ARENA 27          // u32/thread: xp[0..8] | hp[9..25] (17) | pad
// ws (u32, f16-pairs): [p(0,0):0..1920) [p(1,0):1920..3840) [p(0,1):3840..5760) [p(1,1):5760..9856)
// per p<3 pair: W1p[9][32]@+0 | W2p[17][32]@+288 | W3p[34 rows][32 cp]@+832   (rows 32=b3,33=0)
// p3 pair:      W1p@+0 | W2p@+288 | W3p[17 mp][192 c]@+832                     (mp16=(b3,0))
// Weights are read DIRECTLY from global ws with wave-uniform addresses ->
// compiler emits s_load into SGPRs (one fetch per wave, scalar pipe), and
// v_dot2_f32_f16 takes the SGPR as src0. No LDS staging, no __syncthreads.

#if __has_builtin(__builtin_amdgcn_fdot2)
__device__ __forceinline__ float FDOT2(v2h a, v2h b, float c){
  return __builtin_amdgcn_fdot2(a, b, c, false);
}
#else
__device__ __forceinline__ float FDOT2(v2h a, v2h b, float c){
  return fmaf((float)a[0], (float)b[0], fmaf((float)a[1], (float)b[1], c));
}
#endif

__device__ __forceinline__ u32 pkh(float a, float b){
  union { v2fp h; u32 x; } u;
  u.h = __builtin_amdgcn_cvt_pkrtz(a, b);
  return u.x;
}
__device__ __forceinline__ v2h asvh(u32 x){
  union { u32 x; v2h h; } u; u.x = x; return u.h;
}

struct WPtrs { const float* p[24]; };  // pair order (0,0),(1,0),(0,1),(1,1) x {w1,b1,w2,b2,w3,b3}

__global__ __launch_bounds__(256) void prep_kernel(WPtrs S, u32* __restrict__ ws)
{
  const int t = blockIdx.x * 256 + threadIdx.x;
  if (t >= 9856) return;
  int pair, rel;
  if (t < 5760){ pair = t / 1920; rel = t % 1920; }
  else         { pair = 3;        rel = t - 5760; }
  const float* __restrict__ w1 = S.p[pair*6+0];
  const float* __restrict__ b1 = S.p[pair*6+1];
  const float* __restrict__ w2 = S.p[pair*6+2];
  const float* __restrict__ b2 = S.p[pair*6+3];
  const float* __restrict__ w3 = S.p[pair*6+4];
  const float* __restrict__ b3 = S.p[pair*6+5];
  float a, b;
  if (rel < 288){                       // W1p: k-pairs, row 8 pairs (w1[16], b1)
    int kp = rel >> 5, m = rel & 31;
    a = w1[2*kp*32 + m];
    b = (2*kp+1 < 17) ? w1[(2*kp+1)*32 + m] : b1[m];
  } else if (rel < 832){                // W2p: k-pairs, row 16 = (b2, 0)
    int j = rel - 288, kp = j >> 5, m = j & 31;
    if (kp < 16){ a = w2[2*kp*32 + m]; b = w2[(2*kp+1)*32 + m]; }
    else        { a = b2[m];           b = 0.f; }
  } else if (pair < 3){                 // W3p34: c-pairs, rows 32=b3,33=0
    int j = rel - 832, r = j >> 5, cp = j & 31;
    if      (r < 32){ a = w3[r*64 + 2*cp]; b = w3[r*64 + 2*cp + 1]; }
    else if (r ==32){ a = b3[2*cp];        b = b3[2*cp + 1]; }
    else            { a = 0.f;             b = 0.f; }
  } else {                              // W3p17: m-pairs, mp16 = (b3, 0)
    int j = rel - 832, mp = j / 192, c = j % 192;
    if (mp < 16){ a = w3[2*mp*192 + c]; b = w3[(2*mp+1)*192 + c]; }
    else        { a = b3[c];            b = 0.f; }
  }
  ws[t] = pkh(a, b);
}

// radial MLP: xp in A[0..8], hp (h1 then h2) in A[9..24], A[25]=(1,0) const
// W is the GLOBAL ws buffer; pb is a global u32 base (wave-uniform -> s_load)
__device__ __forceinline__ void mlp(const u32* __restrict__ W, int pb, u32* __restrict__ A)
{
  float g[32];
  #pragma unroll
  for (int m = 0; m < 32; ++m) g[m] = 0.f;
  #pragma unroll 1
  for (int kp = 0; kp < 9; ++kp){
    v2h x = asvh(A[kp]);
    const uint4* __restrict__ r4 = (const uint4*)(W + pb + kp*32);
    #pragma unroll
    for (int j = 0; j < 8; ++j){
      uint4 w = r4[j];                               // s_load_dwordx4 (uniform)
      g[4*j+0] = FDOT2(asvh(w.x), x, g[4*j+0]);
      g[4*j+1] = FDOT2(asvh(w.y), x, g[4*j+1]);
      g[4*j+2] = FDOT2(asvh(w.z), x, g[4*j+2]);
      g[4*j+3] = FDOT2(asvh(w.w), x, g[4*j+3]);
    }
  }
  #pragma unroll
  for (int j = 0; j < 16; ++j)
    A[9+j] = pkh(fmaxf(g[2*j], 0.f), fmaxf(g[2*j+1], 0.f));
  float g2[32];
  #pragma unroll
  for (int m = 0; m < 32; ++m) g2[m] = 0.f;
  #pragma unroll 1
  for (int kp = 0; kp < 17; ++kp){                   // kp=16 reads A[25]=(1,0) -> +b2
    v2h x = asvh(A[9+kp]);
    const uint4* __restrict__ r4 = (const uint4*)(W + pb + 288 + kp*32);
    #pragma unroll
    for (int j = 0; j < 8; ++j){
      uint4 w = r4[j];
      g2[4*j+0] = FDOT2(asvh(w.x), x, g2[4*j+0]);
      g2[4*j+1] = FDOT2(asvh(w.y), x, g2[4*j+1]);
      g2[4*j+2] = FDOT2(asvh(w.z), x, g2[4*j+2]);
      g2[4*j+3] = FDOT2(asvh(w.w), x, g2[4*j+3]);
    }
  }
  #pragma unroll
  for (int j = 0; j < 16; ++j)
    A[9+j] = pkh(fmaxf(g2[2*j], 0.f), fmaxf(g2[2*j+1], 0.f));
}

// layer3, 64 cols (c-paired): acc[o] = sum_rows h_r * (w3row . v), bias via rows 32/33
__device__ __forceinline__ void l3a(const u32* __restrict__ W, int wb,
                                    const u32* __restrict__ A,
                                    const u32 (&vp)[4], float (&acc)[8])
{
  #pragma unroll
  for (int o = 0; o < 8; ++o) acc[o] = 0.f;
  #pragma unroll 1
  for (int mp = 0; mp < 17; ++mp){
    v2h hp = asvh(A[9+mp]);
    float h0 = (float)hp[0], h1 = (float)hp[1];
    const uint4* __restrict__ rA = (const uint4*)(W + wb + (2*mp)*32);
    const uint4* __restrict__ rB = rA + 8;
    #pragma unroll
    for (int o = 0; o < 8; ++o){
      uint4 wa = rA[o];                              // s_load (uniform)
      uint4 wb2 = rB[o];
      float tA = 0.f, tB = 0.f;
      tA = FDOT2(asvh(wa.x), asvh(vp[0]), tA);
      tA = FDOT2(asvh(wa.y), asvh(vp[1]), tA);
      tA = FDOT2(asvh(wa.z), asvh(vp[2]), tA);
      tA = FDOT2(asvh(wa.w), asvh(vp[3]), tA);
      tB = FDOT2(asvh(wb2.x), asvh(vp[0]), tB);
      tB = FDOT2(asvh(wb2.y), asvh(vp[1]), tB);
      tB = FDOT2(asvh(wb2.z), asvh(vp[2]), tB);
      tB = FDOT2(asvh(wb2.w), asvh(vp[3]), tB);
      acc[o] = fmaf(h0, tA, fmaf(h1, tB, acc[o]));
    }
  }
}

__global__ __launch_bounds__(TPB, 4) void edge_kernel(
    const float* __restrict__ feat0, const float* __restrict__ feat1,
    const float* __restrict__ wE,    const float* __restrict__ radial,
    const float* __restrict__ b00,   const float* __restrict__ b01,
    const float* __restrict__ b10,   const float* __restrict__ b11,
    const int* __restrict__ src_idx, const u32* __restrict__ ws,
    float* __restrict__ out)
{
  __shared__ u32 AR[TPB * ARENA];      // per-thread arena only (27.6 KB)
  const int tid = threadIdx.x;
  const int cls = blockIdx.x & 1;
  const int e   = (blockIdx.x >> 1) * TPB + tid;
  u32* A = AR + tid * ARENA;

  // edge features -> f16 pairs in arena
  {
    const float4* wp = (const float4*)(wE + (size_t)e * 16);
    float4 a = wp[0], b = wp[1], c = wp[2], d = wp[3];
    A[0] = pkh(a.x, a.y); A[1] = pkh(a.z, a.w);
    A[2] = pkh(b.x, b.y); A[3] = pkh(b.z, b.w);
    A[4] = pkh(c.x, c.y); A[5] = pkh(c.z, c.w);
    A[6] = pkh(d.x, d.y); A[7] = pkh(d.z, d.w);
    A[8] = pkh(radial[e], 1.0f);      // pairs with (w1[16], b1) row
    A[25] = pkh(1.0f, 0.0f);          // constant (1,0) bias selector
  }
  const int idx = src_idx[e];
  // NOTE: no __syncthreads needed — arena is strictly per-thread.

  if (cls == 0){
    // ================= class A: pairs (0,0) + (1,0) -> out0 =================
    const float bB = b00[e];
    float B10[3];
    #pragma unroll
    for (int q = 0; q < 3; ++q) B10[q] = b10[(size_t)e*3 + q];
    u32 vp0[4], vp2[4];
    {
      const float4* f0 = (const float4*)(feat0 + (size_t)idx * 8);
      float4 a = f0[0], b = f0[1];
      vp0[0] = pkh(a.x, a.y); vp0[1] = pkh(a.z, a.w);
      vp0[2] = pkh(b.x, b.y); vp0[3] = pkh(b.z, b.w);
      const float4* f1 = (const float4*)(feat1 + (size_t)idx * 24);
      float s1[24];
      #pragma unroll
      for (int j = 0; j < 6; ++j){
        float4 v = f1[j];
        s1[4*j+0]=v.x; s1[4*j+1]=v.y; s1[4*j+2]=v.z; s1[4*j+3]=v.w;
      }
      float Uv[8];
      #pragma unroll
      for (int i = 0; i < 8; ++i)
        Uv[i] = fmaf(B10[0], s1[3*i+0], fmaf(B10[1], s1[3*i+1], B10[2]*s1[3*i+2]));
      #pragma unroll
      for (int j = 0; j < 4; ++j) vp2[j] = pkh(Uv[2*j], Uv[2*j+1]);
    }
    float msg0[8], acc[8];
    mlp(ws, 0, A);                       // pair (0,0)
    l3a(ws, 832, A, vp0, acc);
    #pragma unroll
    for (int o = 0; o < 8; ++o) msg0[o] = acc[o] * bB;
    mlp(ws, 1920, A);                    // pair (1,0)
    l3a(ws, 1920 + 832, A, vp2, acc);
    #pragma unroll
    for (int o = 0; o < 8; ++o) msg0[o] += acc[o];
    float* o0 = out + (size_t)e * 8;
    ((float4*)o0)[0] = make_float4(msg0[0], msg0[1], msg0[2], msg0[3]);
    ((float4*)o0)[1] = make_float4(msg0[4], msg0[5], msg0[6], msg0[7]);
  } else {
    // ================= class B: pairs (0,1) + (1,1) -> out1 =================
    float B01[3];
    #pragma unroll
    for (int q = 0; q < 3; ++q) B01[q] = b01[(size_t)e*3 + q];
    u32 vp0[4];
    float s1[24];
    {
      const float4* f0 = (const float4*)(feat0 + (size_t)idx * 8);
      float4 a = f0[0], b = f0[1];
      vp0[0] = pkh(a.x, a.y); vp0[1] = pkh(a.z, a.w);
      vp0[2] = pkh(b.x, b.y); vp0[3] = pkh(b.z, b.w);
      const float4* f1 = (const float4*)(feat1 + (size_t)idx * 24);
      #pragma unroll
      for (int j = 0; j < 6; ++j){
        float4 v = f1[j];
        s1[4*j+0]=v.x; s1[4*j+1]=v.y; s1[4*j+2]=v.z; s1[4*j+3]=v.w;
      }
    }
    float t01[8];
    mlp(ws, 3840, A);                    // pair (0,1)
    l3a(ws, 3840 + 832, A, vp0, t01);
    float Bv[27];
    const float* __restrict__ bp = b11 + (size_t)e * 27;
    #pragma unroll
    for (int j = 0; j < 27; ++j) Bv[j] = bp[j];
    mlp(ws, 5760, A);                    // pair (1,1)
    float* o1 = out + (size_t)E_TOT * 8 + (size_t)e * 24;
    #pragma unroll
    for (int o = 0; o < 8; ++o){         // stream 3 results per o -> no msg1[24] live
      float a24[24];
      #pragma unroll
      for (int c = 0; c < 24; ++c) a24[c] = 0.f;
      #pragma unroll 1
      for (int mp = 0; mp < 17; ++mp){   // mp16 row = (b3,0) with hp=(1,0)
        v2h hp = asvh(A[9+mp]);
        const uint4* __restrict__ seg = (const uint4*)(ws + 5760 + 832 + mp*192 + o*24);
        #pragma unroll
        for (int j4 = 0; j4 < 6; ++j4){
          uint4 w = seg[j4];             // s_load (uniform)
          a24[4*j4+0] = FDOT2(asvh(w.x), hp, a24[4*j4+0]);
          a24[4*j4+1] = FDOT2(asvh(w.y), hp, a24[4*j4+1]);
          a24[4*j4+2] = FDOT2(asvh(w.z), hp, a24[4*j4+2]);
          a24[4*j4+3] = FDOT2(asvh(w.w), hp, a24[4*j4+3]);
        }
      }
      float D[9];                        // D[q,f] = sum_i R[o,i,f]*s1[i,q]
      #pragma unroll
      for (int q = 0; q < 3; ++q){
        #pragma unroll
        for (int f = 0; f < 3; ++f){
          float t = 0.f;
          #pragma unroll
          for (int i = 0; i < 8; ++i) t = fmaf(a24[i*3+f], s1[i*3+q], t);
          D[q*3+f] = t;
        }
      }
      #pragma unroll
      for (int p = 0; p < 3; ++p){
        float t = t01[o] * B01[p];
        #pragma unroll
        for (int q = 0; q < 3; ++q){
          #pragma unroll
          for (int f = 0; f < 3; ++f)
            t = fmaf(Bv[p*9 + q*3 + f], D[q*3+f], t);
        }
        o1[o*3 + p] = t;                 // streamed store (merges in L2)
      }
    }
  }
}

extern "C" void kernel_launch(void* const* d_in, const int* in_sizes, int n_in,
                              void* d_out, int out_size, void* d_ws, size_t ws_size,
                              hipStream_t stream)
{
  const float* feat0 = (const float*)d_in[0];
  const float* feat1 = (const float*)d_in[1];
  const float* wE    = (const float*)d_in[2];
  const float* rad   = (const float*)d_in[3];
  const float* b00   = (const float*)d_in[4];
  const float* b01   = (const float*)d_in[11];
  const float* b10   = (const float*)d_in[18];
  const float* b11   = (const float*)d_in[25];
  const int* sidx    = (const int*)d_in[32];
  u32* ws            = (u32*)d_ws;

  // ws pair order: (0,0), (1,0), (0,1), (1,1)  -> d_in weight bases 5, 19, 12, 26
  const int base[4] = {5, 19, 12, 26};
  WPtrs S;
  for (int p = 0; p < 4; ++p)
    for (int k = 0; k < 6; ++k)
      S.p[p*6 + k] = (const float*)d_in[base[p] + k];

  prep_kernel<<<39, 256, 0, stream>>>(S, ws);
  edge_kernel<<<NBLK, TPB, 0, stream>>>(feat0, feat1, wE, rad, b00, b01, b10, b11,
                                        sidx, ws, (float*)d_out);
}